// Round 22
// baseline (56.777 us; speedup 1.0000x reference)
//
#include <hip/hip_runtime.h>

#define NV    500000
#define ND    64
#define NH    4
#define NHID  256
#define NS    10000
#define NOUT  128
#define GSAMP 6                                // samples per block
#define FUSED_GRID ((NS + GSAMP - 1) / GSAMP)  // 1667
#define BOUNDS_BLOCKS ((NV + 255) / 256)       // 1954
#define PREP_GRID (24 + BOUNDS_BLOCKS)

typedef __attribute__((ext_vector_type(8))) _Float16 f16x8;
typedef __attribute__((ext_vector_type(4))) _Float16 f16x4;
typedef __attribute__((ext_vector_type(2))) __fp16   hf16x2;   // cvt_pkrtz result type
typedef __attribute__((ext_vector_type(4))) float    f32x4;

// LDS-only barrier: drain own LDS writes, sync, fence the scheduler.
__device__ __forceinline__ void bar_lds() {
    asm volatile("s_waitcnt lgkmcnt(0)" ::: "memory");
    __builtin_amdgcn_s_barrier();
    __builtin_amdgcn_sched_barrier(0);
}

// ---------------------------------------------------------------------------
// Prep kernel (single launch): Wv->A-frags | Wout->B-frags | bounds.
// ---------------------------------------------------------------------------
__global__ __launch_bounds__(256) void prep_kernel(
    const float* __restrict__ Wv, const float* __restrict__ Wout,
    const int* __restrict__ map,
    _Float16* __restrict__ WfH, _Float16* __restrict__ Wfout,
    int* __restrict__ start)
{
    const int b = blockIdx.x;
    const int t = threadIdx.x;
    if (b < 8) {
        const int tid  = b * 256 + t;
        const int lane = tid & 63;
        const int slot = tid >> 6;
        const int ks   = slot & 1;
        const int jt   = (slot >> 1) & 3;
        const int h    = slot >> 3;
        const int j    = h * 64 + jt * 16 + (lane & 15);
        const int kb   = ks * 32 + (lane >> 4) * 8;
        f16x8 hv;
#pragma unroll
        for (int i = 0; i < 8; ++i)
            hv[i] = (_Float16)Wv[(size_t)(kb + i) * NHID + j];
        *reinterpret_cast<f16x8*>(WfH + ((size_t)slot << 9) + (lane << 3)) = hv;
    } else if (b < 24) {
        const int tid2 = (b - 8) * 256 + t;
        const int lane = tid2 & 63;
        const int slot = tid2 >> 6;           // nt*8 + ks
        const int ks   = slot & 7;
        const int nt   = slot >> 3;
        const int n    = (nt << 4) + (lane & 15);
        const int kb   = (ks << 5) + ((lane >> 4) << 3);
        f16x8 hv;
#pragma unroll
        for (int i = 0; i < 8; ++i)
            hv[i] = (_Float16)Wout[(size_t)(kb + i) * NOUT + n];
        *reinterpret_cast<f16x8*>(Wfout + ((size_t)slot << 9) + (lane << 3)) = hv;
    } else {
        const int v = (b - 24) * 256 + t;
        if (v >= NV) return;
        const int cur = map[v];
        if (v == 0) {
            for (int s = 0; s <= cur; ++s) start[s] = 0;
        } else {
            const int prev = map[v - 1];
            for (int s = prev + 1; s <= cur; ++s) start[s] = v;
        }
        if (v == NV - 1) {
            for (int s = cur + 1; s <= NS; ++s) start[s] = NV;
        }
    }
}

// ---------------------------------------------------------------------------
// Fused (R22): R21 structure but SINGLE EHt buffer + third LDS-only barrier
// (PV -> barC -> stage). LDS 36.4 -> 27.9 KB => 5 blocks/CU (+25% TLP).
// Dependency order: scores(i)->barA->PV(i)->barC->stage(i+1)->barB->scores(i+1).
// Numerics identical to R20/R21.
// ---------------------------------------------------------------------------
__global__ __launch_bounds__(256, 4) void fused_kernel(
    const float* __restrict__ emb,
    const _Float16* __restrict__ WfH, const _Float16* __restrict__ Wfout,
    const int* __restrict__ start, float* __restrict__ out)
{
    __shared__ _Float16 EH[64 * 64];      // emb hi, row-major swizzled (8 KB)
    __shared__ _Float16 EHt[64 * 68];     // emb hi, d-major, v'-permuted (8.5 KB)
    __shared__ _Float16 ELDS[16][72];     // e-matrix, k-permuted, padded (2.25 KB)
    __shared__ _Float16 PFL[16][264];     // pooled rows (f16), padded (8.25 KB)
    __shared__ float    rbuf[NH];
    __shared__ float    lbuf[NH];

    const int t    = threadIdx.x;
    const int lane = t & 63;
    const int h    = t >> 6;
    const int vcol = lane & 15;
    const int g    = lane >> 4;

    f16x8 wh[4][2];
#pragma unroll
    for (int jt = 0; jt < 4; ++jt)
#pragma unroll
        for (int ks = 0; ks < 2; ++ks) {
            const int slot = ((h * 4 + jt) * 2 + ks);
            wh[jt][ks] = *reinterpret_cast<const f16x8*>(
                WfH + ((size_t)slot << 9) + (lane << 3));
        }

    for (int i = t; i < (16 * 72 * 2) / 4; i += 256)
        reinterpret_cast<unsigned*>(ELDS)[i] = 0u;
    for (int i = t; i < (16 * 264 * 2) / 4; i += 256)
        reinterpret_cast<unsigned*>(PFL)[i] = 0u;
    __syncthreads();

    const int s0   = blockIdx.x * GSAMP;
    const int sEnd = (s0 + GSAMP < NS) ? (s0 + GSAMP) : NS;
    const int srow = t >> 4;
    const int sk4  = (t & 15) << 2;
    const int woff = (srow << 7) + ((sk4 << 1) ^ ((srow & 7) << 4));

    const int dpv  = (h << 4) + vcol;
    const int pvb  = dpv * 136 + (g << 4);
    const int epos = ((lane & 15) << 2) + (lane >> 4);

    int s = s0, st = 0, en = 0;
    while (s < sEnd) {
        st = start[s]; en = start[s + 1];
        if (st < en) break;
        ++s;
    }

    const float4 z4 = make_float4(0.f, 0.f, 0.f, 0.f);

#define CONV_STAGE(X0, X1, X2, X3, CC)                                        \
    {                                                                         \
        const float4 y0 = (srow      < (CC)) ? (X0) : z4;                     \
        const float4 y1 = (srow + 16 < (CC)) ? (X1) : z4;                     \
        const float4 y2 = (srow + 32 < (CC)) ? (X2) : z4;                     \
        const float4 y3 = (srow + 48 < (CC)) ? (X3) : z4;                     \
        f16x4 hv0, hv1, hv2, hv3;                                             \
        {                                                                     \
            const hf16x2 a01 = __builtin_amdgcn_cvt_pkrtz(y0.x, y0.y);        \
            const hf16x2 a23 = __builtin_amdgcn_cvt_pkrtz(y0.z, y0.w);        \
            hv0[0] = (_Float16)a01[0]; hv0[1] = (_Float16)a01[1];             \
            hv0[2] = (_Float16)a23[0]; hv0[3] = (_Float16)a23[1];             \
            const hf16x2 b01 = __builtin_amdgcn_cvt_pkrtz(y1.x, y1.y);        \
            const hf16x2 b23 = __builtin_amdgcn_cvt_pkrtz(y1.z, y1.w);        \
            hv1[0] = (_Float16)b01[0]; hv1[1] = (_Float16)b01[1];             \
            hv1[2] = (_Float16)b23[0]; hv1[3] = (_Float16)b23[1];             \
            const hf16x2 c01 = __builtin_amdgcn_cvt_pkrtz(y2.x, y2.y);        \
            const hf16x2 c23 = __builtin_amdgcn_cvt_pkrtz(y2.z, y2.w);        \
            hv2[0] = (_Float16)c01[0]; hv2[1] = (_Float16)c01[1];             \
            hv2[2] = (_Float16)c23[0]; hv2[3] = (_Float16)c23[1];             \
            const hf16x2 d01 = __builtin_amdgcn_cvt_pkrtz(y3.x, y3.y);        \
            const hf16x2 d23 = __builtin_amdgcn_cvt_pkrtz(y3.z, y3.w);        \
            hv3[0] = (_Float16)d01[0]; hv3[1] = (_Float16)d01[1];             \
            hv3[2] = (_Float16)d23[0]; hv3[3] = (_Float16)d23[1];             \
        }                                                                     \
        *reinterpret_cast<f16x4*>((char*)EH + woff)             = hv0;        \
        *reinterpret_cast<f16x4*>((char*)EH + woff + (1 << 11)) = hv1;        \
        *reinterpret_cast<f16x4*>((char*)EH + woff + (2 << 11)) = hv2;        \
        *reinterpret_cast<f16x4*>((char*)EH + woff + (3 << 11)) = hv3;        \
        _Pragma("unroll")                                                     \
        for (int jj = 0; jj < 4; ++jj) {                                      \
            const int d = sk4 + jj;                                           \
            f16x4 w4;                                                         \
            w4[0] = hv0[jj]; w4[1] = hv1[jj]; w4[2] = hv2[jj]; w4[3] = hv3[jj];\
            *reinterpret_cast<f16x4*>((char*)EHt + d * 136 + (srow << 3)) = w4; \
        }                                                                     \
    }

    if (s < sEnd) {
        int c0 = st;

        // ---- prologue: stage first chunk ----
        {
            const int C = min(64, en - c0);
            float4 x0 = (srow      < C) ? *reinterpret_cast<const float4*>(emb + (size_t)(c0 + srow     ) * ND + sk4) : z4;
            float4 x1 = (srow + 16 < C) ? *reinterpret_cast<const float4*>(emb + (size_t)(c0 + srow + 16) * ND + sk4) : z4;
            float4 x2 = (srow + 32 < C) ? *reinterpret_cast<const float4*>(emb + (size_t)(c0 + srow + 32) * ND + sk4) : z4;
            float4 x3 = (srow + 48 < C) ? *reinterpret_cast<const float4*>(emb + (size_t)(c0 + srow + 48) * ND + sk4) : z4;
            CONV_STAGE(x0, x1, x2, x3, C)
        }
        __syncthreads();

        f32x4 acc = {0.f, 0.f, 0.f, 0.f};
        float m = -1e30f, l = 0.f;

        for (;;) {
            const int C = min(64, en - c0);
            const bool lastOfSample = (c0 + 64 >= en);

            // ---- locate next chunk + issue its loads (chunk top) ----
            int ns = s, nc0 = c0 + 64, nen = en;
            if (lastOfSample) {
                ns = s + 1; nc0 = 0; nen = 0;
                while (ns < sEnd) {
                    const int a = start[ns], bb = start[ns + 1];
                    if (a < bb) { nc0 = a; nen = bb; break; }
                    ++ns;
                }
            }
            const bool hasNext = (ns < sEnd) && (nc0 < nen);
            float4 x0 = z4, x1 = z4, x2 = z4, x3 = z4;
            int nC = 0;
            if (hasNext) {
                nC = min(64, nen - nc0);
                if (srow      < nC) x0 = *reinterpret_cast<const float4*>(emb + (size_t)(nc0 + srow     ) * ND + sk4);
                if (srow + 16 < nC) x1 = *reinterpret_cast<const float4*>(emb + (size_t)(nc0 + srow + 16) * ND + sk4);
                if (srow + 32 < nC) x2 = *reinterpret_cast<const float4*>(emb + (size_t)(nc0 + srow + 32) * ND + sk4);
                if (srow + 48 < nC) x3 = *reinterpret_cast<const float4*>(emb + (size_t)(nc0 + srow + 48) * ND + sk4);
            }

            // ---- scores for head h; only occupied v-tiles ----
            float sv[4];
            __builtin_amdgcn_s_setprio(1);
#pragma unroll
            for (int vt = 0; vt < 4; ++vt) {
                float sreg = 0.f;
                if ((vt << 4) < C) {
                    const int row = (vt << 4) + vcol;
                    const int rb  = row << 7;
                    const int sw  = (row & 7) << 4;
                    const f16x8 bh0 = *reinterpret_cast<const f16x8*>(
                        (const char*)EH + rb + (((g << 4)) ^ sw));
                    const f16x8 bh1 = *reinterpret_cast<const f16x8*>(
                        (const char*)EH + rb + ((64 | (g << 4)) ^ sw));
#pragma unroll
                    for (int jt = 0; jt < 4; ++jt) {
                        f32x4 a4 = {0.f, 0.f, 0.f, 0.f};
                        a4 = __builtin_amdgcn_mfma_f32_16x16x32_f16(wh[jt][0], bh0, a4, 0, 0, 0);
                        a4 = __builtin_amdgcn_mfma_f32_16x16x32_f16(wh[jt][1], bh1, a4, 0, 0, 0);
                        sreg += a4[0]*a4[0] + a4[1]*a4[1] + a4[2]*a4[2] + a4[3]*a4[3];
                    }
                    sreg += __shfl_xor(sreg, 16, 64);
                    sreg += __shfl_xor(sreg, 32, 64);
                }
                sv[vt] = sreg;
            }
            __builtin_amdgcn_s_setprio(0);

            const float scA = (lane & 16) ? sv[1] : sv[0];
            const float scB = (lane & 16) ? sv[3] : sv[2];
            const float scO = (lane & 32) ? scB : scA;

            // ---- online softmax update ----
            const float sc = (lane < C) ? scO : -1e30f;
            float cmax = sc;
#pragma unroll
            for (int off = 1; off < 64; off <<= 1)
                cmax = fmaxf(cmax, __shfl_xor(cmax, off, 64));
            const float mn = fmaxf(m, cmax);
            const float r  = __expf(m - mn);
            const float e  = (lane < C) ? __expf(sc - mn) : 0.f;
            float csum = e;
#pragma unroll
            for (int off = 1; off < 64; off <<= 1)
                csum += __shfl_xor(csum, off, 64);
            l = l * r + csum;
            m = mn;

            // ---- publish e, r, (l if last) ----
            ELDS[h][epos] = (_Float16)e;
            if (lane == 0) { rbuf[h] = r; if (lastOfSample) lbuf[h] = l; }

            bar_lds();   // barA: e/rbuf/lbuf visible; scores' EH reads done

            // ---- PV ----
            {
                const float rb0 = rbuf[0], rb1 = rbuf[1], rb2 = rbuf[2], rb3 = rbuf[3];
                const f16x8 ea0 = *reinterpret_cast<const f16x8*>(&ELDS[vcol][g << 3]);
                const f16x8 ea1 = *reinterpret_cast<const f16x8*>(&ELDS[vcol][(g << 3) + 32]);
                const f16x4 b0lo = *reinterpret_cast<const f16x4*>((const char*)EHt + pvb);
                const f16x4 b0hi = *reinterpret_cast<const f16x4*>((const char*)EHt + pvb + 8);
                const f16x4 b1lo = *reinterpret_cast<const f16x4*>((const char*)EHt + pvb + 64);
                const f16x4 b1hi = *reinterpret_cast<const f16x4*>((const char*)EHt + pvb + 72);
                f16x8 eb0, eb1;
                eb0[0]=b0lo[0]; eb0[1]=b0lo[1]; eb0[2]=b0lo[2]; eb0[3]=b0lo[3];
                eb0[4]=b0hi[0]; eb0[5]=b0hi[1]; eb0[6]=b0hi[2]; eb0[7]=b0hi[3];
                eb1[0]=b1lo[0]; eb1[1]=b1lo[1]; eb1[2]=b1lo[2]; eb1[3]=b1lo[3];
                eb1[4]=b1hi[0]; eb1[5]=b1hi[1]; eb1[6]=b1hi[2]; eb1[7]=b1hi[3];
                acc[0] *= rb0; acc[1] *= rb1; acc[2] *= rb2; acc[3] *= rb3;
                acc = __builtin_amdgcn_mfma_f32_16x16x32_f16(ea0, eb0, acc, 0, 0, 0);
                acc = __builtin_amdgcn_mfma_f32_16x16x32_f16(ea1, eb1, acc, 0, 0, 0);
            }

            bar_lds();   // barC: PV's EHt/ELDS reads done before restage

            // ---- convert + stage next chunk (same EHt buffer) ----
            if (hasNext)
                CONV_STAGE(x0, x1, x2, x3, nC)

            // ---- sample end: normalized pooled row -> PFL (f16) ----
            if (lastOfSample) {
                if (g == 0) {
                    const int si = s - s0;
#pragma unroll
                    for (int rr = 0; rr < 4; ++rr)
                        PFL[si][rr * 64 + (h << 4) + vcol] =
                            (_Float16)(acc[rr] / lbuf[rr]);
                }
                acc[0] = acc[1] = acc[2] = acc[3] = 0.f;
                m = -1e30f; l = 0.f;
                s = ns; c0 = nc0; en = nen;
            } else {
                c0 = nc0;
            }

            if (!hasNext) break;
            bar_lds();   // barB: stage visible before next scores
        }
    }

    // ---- fused output projection: out[s0+m][:] = PFL[m][:] @ W_out ----
    __syncthreads();
#pragma unroll
    for (int ntl = 0; ntl < 2; ++ntl) {
        const int nt = (h << 1) + ntl;
        f32x4 ao = {0.f, 0.f, 0.f, 0.f};
#pragma unroll
        for (int ks = 0; ks < 8; ++ks) {
            const f16x8 a = *reinterpret_cast<const f16x8*>(
                (const char*)PFL + vcol * 528 + (((ks << 5) + (g << 3)) << 1));
            const f16x8 bq = *reinterpret_cast<const f16x8*>(
                Wfout + ((size_t)((nt << 3) + ks) << 9) + (lane << 3));
            ao = __builtin_amdgcn_mfma_f32_16x16x32_f16(a, bq, ao, 0, 0, 0);
        }
#pragma unroll
        for (int rr = 0; rr < 4; ++rr) {
            const int sm = (g << 2) + rr;
            if (sm < GSAMP && s0 + sm < NS)
                out[(size_t)(s0 + sm) * NOUT + (nt << 4) + vcol] = ao[rr];
        }
    }
#undef CONV_STAGE
}

// ---------------------------------------------------------------------------
extern "C" void kernel_launch(void* const* d_in, const int* in_sizes, int n_in,
                              void* d_out, int out_size, void* d_ws, size_t ws_size,
                              hipStream_t stream)
{
    const float* emb  = (const float*)d_in[0];
    const float* Wv   = (const float*)d_in[1];
    const float* Wout = (const float*)d_in[2];
    const int*   map  = (const int*)d_in[3];
    float* out = (float*)d_out;

    char* ws = (char*)d_ws;
    int*      start = (int*)ws;                       //  40,004 B
    _Float16* WfH   = (_Float16*)(ws + 40064);        //  32,768 B
    _Float16* Wfout = (_Float16*)(ws + 72832);        //  65,536 B

    prep_kernel<<<PREP_GRID, 256, 0, stream>>>(Wv, Wout, map, WfH, Wfout, start);
    fused_kernel<<<FUSED_GRID, 256, 0, stream>>>(emb, WfH, Wfout, start, out);
}